// Round 1
// baseline (200.163 us; speedup 1.0000x reference)
//
#include <hip/hip_runtime.h>
#include <hip/hip_bf16.h>
#include <math.h>

#define N_INIT 20000
#define LVLS   32
#define PP     1024
#define DD     64
#define DEE    128
#define N_TOT  (N_INIT + LVLS * PP)   // 52768

// workspace layout (floats): [0, N_TOT*DD) = store
// at byte offset ACC_OFF: int acc_i[4] = {n_good, n_sel, cnt_pos, cnt_negok}
// at ACC_OFF+16: float acc_f[1] = {loss}
#define STORE_FLOATS (N_TOT * DD)
#define ACC_OFF ((size_t)STORE_FLOATS * 4)

__device__ __forceinline__ float softplusf(float x) {
    return fmaxf(x, 0.f) + log1pf(expf(-fabsf(x)));
}

__global__ __launch_bounds__(256) void init_kernel(
    float* __restrict__ store, const int* __restrict__ thax,
    const float* __restrict__ init_table,
    const int* __restrict__ sel_mask, const int* __restrict__ good_mask,
    int* __restrict__ acc_i)
{
    int idx = blockIdx.x * 256 + threadIdx.x;
    if (idx < N_INIT * DD) {
        int i = idx >> 6, d = idx & 63;
        store[idx] = init_table[thax[i] * DD + d];
    }
    bool v  = idx < N_TOT;
    int  sm = v ? sel_mask[idx]  : 0;
    int  gm = v ? good_mask[idx] : 0;
    bool sel  = sm > 0;
    bool good = (gm > 0) && sel;
    unsigned long long ms = __ballot(sel);
    unsigned long long mg = __ballot(good);
    if ((threadIdx.x & 63) == 0) {
        if (mg) atomicAdd(&acc_i[0], __popcll(mg));
        if (ms) atomicAdd(&acc_i[1], __popcll(ms));
    }
}

// one block (1 wave, 64 threads) per node
__global__ __launch_bounds__(64) void level_kernel(
    float* __restrict__ store,
    const int* __restrict__ parents, const int* __restrict__ rules,
    const float* __restrict__ W_rule, const float* __restrict__ b_rule,
    int l)
{
    int p = blockIdx.x;
    int j = threadIdx.x;             // 0..63
    int base = N_INIT + l * PP;
    int pa = parents[(l * PP + p) * 2 + 0];
    int pb = parents[(l * PP + p) * 2 + 1];
    int r  = rules[l * PP + p];

    __shared__ float pe[2 * DD];
    pe[j]      = store[(size_t)pa * DD + j];
    pe[j + DD] = store[(size_t)pb * DD + j];
    __syncthreads();

    const float* __restrict__ W = W_rule + (size_t)r * (2 * DD * DD);
    float a0 = 0.f, a1 = 0.f, a2 = 0.f, a3 = 0.f;
#pragma unroll
    for (int i = 0; i < 2 * DD; i += 4) {
        a0 = fmaf(pe[i + 0], W[(i + 0) * DD + j], a0);
        a1 = fmaf(pe[i + 1], W[(i + 1) * DD + j], a1);
        a2 = fmaf(pe[i + 2], W[(i + 2) * DD + j], a2);
        a3 = fmaf(pe[i + 3], W[(i + 3) * DD + j], a3);
    }
    float acc = ((a0 + a1) + (a2 + a3)) + b_rule[r * DD + j];
    store[((size_t)(base + p)) * DD + j] = fmaxf(acc, 0.f);
}

__global__ __launch_bounds__(256) void eval_kernel(
    const float* __restrict__ store,
    const float* __restrict__ W1, const float* __restrict__ b1,
    const float* __restrict__ w2, const float* __restrict__ b2,
    const int* __restrict__ sel_mask, const int* __restrict__ good_mask,
    int* __restrict__ acc_i, float* __restrict__ acc_f)
{
    __shared__ float sW1[DD * DEE];   // [d][j] layout, 32 KB
    __shared__ float sb1[DEE];
    __shared__ float sw2[DEE];

    for (int t = threadIdx.x; t < (DD * DEE) / 4; t += 256)
        ((float4*)sW1)[t] = ((const float4*)W1)[t];
    if (threadIdx.x < DEE) {
        sb1[threadIdx.x] = b1[threadIdx.x];
        sw2[threadIdx.x] = w2[threadIdx.x];
    }
    __syncthreads();

    int i = blockIdx.x * 256 + threadIdx.x;
    bool valid = i < N_TOT;

    float logit = 0.f;
    if (valid) {
        float s[DD];
        const float4* sp = (const float4*)(store + (size_t)i * DD);
#pragma unroll
        for (int k = 0; k < DD / 4; ++k) {
            float4 v = sp[k];
            s[4 * k + 0] = v.x; s[4 * k + 1] = v.y;
            s[4 * k + 2] = v.z; s[4 * k + 3] = v.w;
        }
        logit = b2[0];
        const float4* Wv = (const float4*)sW1;
        for (int jq = 0; jq < DEE / 4; ++jq) {
            float4 a = ((const float4*)sb1)[jq];
#pragma unroll
            for (int d = 0; d < DD; ++d) {
                float4 w = Wv[d * (DEE / 4) + jq];
                a.x = fmaf(s[d], w.x, a.x);
                a.y = fmaf(s[d], w.y, a.y);
                a.z = fmaf(s[d], w.z, a.z);
                a.w = fmaf(s[d], w.w, a.w);
            }
            float4 wv2 = ((const float4*)sw2)[jq];
            logit += fmaxf(a.x, 0.f) * wv2.x + fmaxf(a.y, 0.f) * wv2.y +
                     fmaxf(a.z, 0.f) * wv2.z + fmaxf(a.w, 0.f) * wv2.w;
        }
    }

    int sm = valid ? sel_mask[i]  : 0;
    int gm = valid ? good_mask[i] : 0;
    bool sel  = sm > 0;
    bool good = (gm > 0) && sel;

    int ng = acc_i[0];
    int ns = acc_i[1];
    int nn = ns - ng;
    float pos_w = ng > 0 ? 0.85f / (float)ng : 1.0f;
    float neg_w = nn > 0 ? 0.15f / (float)nn : 1.0f;

    float bce = softplusf(logit) - logit * (good ? 1.f : 0.f);
    float w   = (good ? pos_w : neg_w) * (sel ? 1.f : 0.f);
    float contrib = valid ? w * bce : 0.f;

    bool pos_hit = valid && good && (logit >= 0.f);
    bool neg_hit = valid && sel && !good && (logit < 0.f);

    int lane = threadIdx.x & 63;
    int wid  = threadIdx.x >> 6;
    float c = contrib;
    for (int off = 32; off; off >>= 1) c += __shfl_down(c, off, 64);

    unsigned long long mp = __ballot(pos_hit);
    unsigned long long mn = __ballot(neg_hit);

    __shared__ float wsums[4];
    if (lane == 0) {
        wsums[wid] = c;
        if (mp) atomicAdd(&acc_i[2], __popcll(mp));
        if (mn) atomicAdd(&acc_i[3], __popcll(mn));
    }
    __syncthreads();
    if (threadIdx.x == 0)
        atomicAdd(acc_f, (wsums[0] + wsums[1]) + (wsums[2] + wsums[3]));
}

__global__ void finalize_kernel(float* __restrict__ out,
                                const int* __restrict__ acc_i,
                                const float* __restrict__ acc_f)
{
    int ng = acc_i[0], ns = acc_i[1];
    int nn = ns - ng;
    out[0] = acc_f[0];
    out[1] = ng > 0 ? (float)acc_i[2] / (float)ng : 1.0f;
    out[2] = nn > 0 ? (float)acc_i[3] / (float)nn : 1.0f;
}

extern "C" void kernel_launch(void* const* d_in, const int* in_sizes, int n_in,
                              void* d_out, int out_size, void* d_ws, size_t ws_size,
                              hipStream_t stream) {
    const int*   thax       = (const int*)d_in[0];
    const int*   parents    = (const int*)d_in[1];
    const int*   rules      = (const int*)d_in[2];
    const int*   sel_mask   = (const int*)d_in[3];
    const int*   good_mask  = (const int*)d_in[4];
    const float* init_table = (const float*)d_in[5];
    const float* W_rule     = (const float*)d_in[6];
    const float* b_rule     = (const float*)d_in[7];
    const float* W1         = (const float*)d_in[8];
    const float* b1         = (const float*)d_in[9];
    const float* w2         = (const float*)d_in[10];
    const float* b2         = (const float*)d_in[11];

    float* store = (float*)d_ws;
    int*   acc_i = (int*)((char*)d_ws + ACC_OFF);
    float* acc_f = (float*)((char*)d_ws + ACC_OFF + 16);

    hipMemsetAsync((char*)d_ws + ACC_OFF, 0, 32, stream);

    init_kernel<<<(N_INIT * DD + 255) / 256, 256, 0, stream>>>(
        store, thax, init_table, sel_mask, good_mask, acc_i);

    for (int l = 0; l < LVLS; ++l)
        level_kernel<<<PP, 64, 0, stream>>>(store, parents, rules, W_rule, b_rule, l);

    eval_kernel<<<(N_TOT + 255) / 256, 256, 0, stream>>>(
        store, W1, b1, w2, b2, sel_mask, good_mask, acc_i, acc_f);

    finalize_kernel<<<1, 1, 0, stream>>>((float*)d_out, acc_i, acc_f);
}